// Round 10
// baseline (4965.850 us; speedup 1.0000x reference)
//
#include <hip/hip_runtime.h>

#define NN 8000
#define EE 200000
#define BB 16
#define DD 256
#define LL 4
#define KF 600
#define HEPAD 280
#define ASPAD 40

typedef unsigned short bf16;
typedef short bf16x8 __attribute__((ext_vector_type(8)));
typedef float f32x4 __attribute__((ext_vector_type(4)));

__device__ __forceinline__ float b2f(bf16 u) { return __uint_as_float(((unsigned)u) << 16); }
__device__ __forceinline__ bf16 f2b(float f) {
    unsigned u = __float_as_uint(f);
    u = u + 0x7fffu + ((u >> 16) & 1u);
    return (bf16)(u >> 16);
}

// ---------------- setup ----------------

__global__ void k_lfeat(const float* __restrict__ lat, float* __restrict__ lf) {
    int t = threadIdx.x;
    if (t >= BB * 6) return;
    int b = t / 6, p = t % 6;
    const int rr[6] = {0, 0, 0, 1, 1, 2};
    const int cc[6] = {0, 1, 2, 1, 2, 2};
    float acc = 0.f;
    for (int i = 0; i < 3; i++)
        acc += lat[b * 9 + i * 3 + rr[p]] * lat[b * 9 + i * 3 + cc[p]];
    lf[b * 6 + p] = acc;
}

__global__ void k_zero(int* __restrict__ p, int n) {
    int i = blockIdx.x * 256 + threadIdx.x;
    if (i < n) p[i] = 0;
}

__global__ void k_zerof(float* __restrict__ p, int n) {
    int i = blockIdx.x * 256 + threadIdx.x;
    if (i < n) p[i] = 0.f;
}

__global__ void k_count(const int* __restrict__ src, int* __restrict__ counts) {
    int e = blockIdx.x * 256 + threadIdx.x;
    if (e < EE) atomicAdd(&counts[src[e]], 1);
}

__global__ void k_scan(const int* __restrict__ counts, int* __restrict__ starts,
                       int* __restrict__ cursor) {
    __shared__ int ssum[256];
    int tid = threadIdx.x;
    int base = tid * 32;
    int local = 0;
    for (int i = 0; i < 32; i++) {
        int r = base + i;
        if (r < NN) local += counts[r];
    }
    ssum[tid] = local;
    __syncthreads();
    for (int off = 1; off < 256; off <<= 1) {
        int v = (tid >= off) ? ssum[tid - off] : 0;
        __syncthreads();
        ssum[tid] += v;
        __syncthreads();
    }
    int run = (tid == 0) ? 0 : ssum[tid - 1];
    for (int i = 0; i < 32; i++) {
        int r = base + i;
        if (r < NN) {
            starts[r] = run;
            cursor[r] = run;
            run += counts[r];
        }
    }
    if (tid == 255) starts[NN] = ssum[255];
}

__global__ void k_scatter(const int* __restrict__ src, int* __restrict__ cursor,
                          int* __restrict__ eids) {
    int e = blockIdx.x * 256 + threadIdx.x;
    if (e >= EE) return;
    int pos = atomicAdd(&cursor[src[e]], 1);
    eids[pos] = e;
}

__global__ void k_node_init(const int* __restrict__ at, const int* __restrict__ bid,
                            const float* __restrict__ emb, const float* __restrict__ W,
                            const float* __restrict__ nb, const float* __restrict__ lf,
                            float* __restrict__ hn) {
    __shared__ float arow[262];
    int n = blockIdx.x, d = threadIdx.x;
    arow[d] = emb[at[n] * DD + d];
    if (d < 6) arow[256 + d] = lf[bid[n] * 6 + d];
    __syncthreads();
    float acc = nb[d];
    for (int k = 0; k < 262; k++) acc += arow[k] * W[k * DD + d];
    hn[n * DD + d] = acc;
}

__global__ void k_cvt(const float* __restrict__ src, bf16* __restrict__ dst, int n) {
    int i = blockIdx.x * 256 + threadIdx.x;
    if (i < n) dst[i] = f2b(src[i]);
}

// ---------------- swizzled panel builder ----------------

__global__ void k_panel(const float* __restrict__ W, int ldw, int c0, size_t wlstride,
                        int Ktot, bf16* __restrict__ dst, int pcount) {
    int p = blockIdx.x, l = blockIdx.y, g = blockIdx.z, n = threadIdx.x;
    const float* Wl = W + (size_t)l * wlstride;
    bf16* d = dst + (((size_t)(l * gridDim.z + g)) * pcount + p) * 8192;
    int c = c0 + g * 256 + n;
    for (int kk = 0; kk < 32; kk++) {
        int k = p * 32 + kk;
        float v = (k < Ktot) ? Wl[(size_t)k * ldw + c] : 0.f;
        int swz = ((((kk >> 3) + ((n >> 1) & 3)) & 3)) * 8 + (kk & 7);
        d[n * 32 + swz] = f2b(v);
    }
}

// ---------------- MFMA QK kernel (4x4 frag reuse, dbuf staging) ----------------

__global__ void __launch_bounds__(256) k_qk_mfma(
    const bf16* __restrict__ hnb, const int* __restrict__ src, const int* __restrict__ dst,
    const float* __restrict__ frac, const float* __restrict__ shifts,
    const uint4* __restrict__ WeP, const float* __restrict__ be,
    const uint4* __restrict__ QP, const uint4* __restrict__ KP,
    const float* __restrict__ bq, const float* __restrict__ bkv,
    float* __restrict__ scores) {
    __shared__ bf16 heb[64][HEPAD];
    __shared__ bf16 As[2][64][ASPAD];
    __shared__ bf16 Bsm[2][8192];
    __shared__ float dsv[64][3];
    __shared__ int sid[64], did[64];

    int tid = threadIdx.x;
    int wv = tid >> 6, lane = tid & 63, quad = lane >> 4, m = lane & 15;
    int e0 = blockIdx.x * 64;
    if (tid < 64) {
        int e = e0 + tid;
        int sn = src[e], dn = dst[e];
        sid[tid] = sn; did[tid] = dn;
#pragma unroll
        for (int c = 0; c < 3; c++) {
            float a = frac[dn * 3 + c] - frac[sn * 3 + c] + shifts[e * 3 + c];
            dsv[tid][c] = a - floorf(a);
        }
    }
    __syncthreads();

    int ar = tid >> 2, kb = (tid & 3) * 8;
    float d0 = dsv[ar][0], d1 = dsv[ar][1], d2 = dsv[ar][2];
    int n0 = 64 * wv;

    auto stageF = [&](int p, int buf) {
        bf16 t8[8];
#pragma unroll
        for (int j = 0; j < 8; j++) {
            int k = p * 32 + kb + j;
            float v = 0.f;
            if (k < KF) {
                int jj = (k < 300) ? k : k - 300;
                int c = jj / 100;
                int f = jj - c * 100;
                float d = (c == 0) ? d0 : ((c == 1) ? d1 : d2);
                float ang = 6.283185307179586f * d * (float)f;
                v = (k < 300) ? __sinf(ang) : __cosf(ang);
            }
            t8[j] = f2b(v);
        }
        *(uint4*)&As[buf][ar][kb] = *(const uint4*)t8;
    };
    auto stageH = [&](const int* ids, int p, int buf) {
        *(uint4*)&As[buf][ar][kb] = *(const uint4*)&hnb[(size_t)ids[ar] * 256 + p * 32 + kb];
    };
    auto stageB = [&](const uint4* P, int p, int buf) {
        const uint4* g = P + (size_t)p * 1024;
        uint4* s = (uint4*)&Bsm[buf][0];
#pragma unroll
        for (int i = 0; i < 4; i++) s[tid + i * 256] = g[tid + i * 256];
    };
    auto bfr = [&](int buf, int c) -> bf16x8 {
        int n = n0 + 16 * c + m;
        int q2 = (quad + ((n >> 1) & 3)) & 3;
        return *(const bf16x8*)&Bsm[buf][n * 32 + q2 * 8];
    };

    // ---- stage 1: he = F @ We + be
    {
        f32x4 acc[4][4];
#pragma unroll
        for (int r = 0; r < 4; r++)
#pragma unroll
            for (int c = 0; c < 4; c++) acc[r][c] = (f32x4){0.f, 0.f, 0.f, 0.f};
        stageF(0, 0); stageB(WeP, 0, 0);
        __syncthreads();
        for (int p = 0; p < 19; p++) {
            int cur = p & 1, nxt = cur ^ 1;
            if (p < 18) { stageF(p + 1, nxt); stageB(WeP, p + 1, nxt); }
            bf16x8 a[4], b[4];
#pragma unroll
            for (int r = 0; r < 4; r++) a[r] = *(const bf16x8*)&As[cur][16 * r + m][quad * 8];
#pragma unroll
            for (int c = 0; c < 4; c++) b[c] = bfr(cur, c);
#pragma unroll
            for (int r = 0; r < 4; r++)
#pragma unroll
                for (int c = 0; c < 4; c++)
                    acc[r][c] = __builtin_amdgcn_mfma_f32_16x16x32_bf16(a[r], b[c], acc[r][c], 0, 0, 0);
            __syncthreads();
        }
#pragma unroll
        for (int r = 0; r < 4; r++)
#pragma unroll
            for (int c = 0; c < 4; c++) {
                int col = n0 + 16 * c + m;
                float bias = be[col];
#pragma unroll
                for (int rr = 0; rr < 4; rr++)
                    heb[16 * r + quad * 4 + rr][col] = f2b(acc[r][c][rr] + bias);
            }
    }
    __syncthreads();

    // ---- stage 2a: Q
    f32x4 qa[4][4];
#pragma unroll
    for (int r = 0; r < 4; r++)
#pragma unroll
        for (int c = 0; c < 4; c++) qa[r][c] = (f32x4){0.f, 0.f, 0.f, 0.f};
    stageH(sid, 0, 0); stageB(QP, 0, 0);
    __syncthreads();
    for (int p = 0; p < 16; p++) {
        int cur = p & 1, nxt = cur ^ 1;
        if (p < 15) { stageB(QP, p + 1, nxt); if (p + 1 < 8) stageH(sid, p + 1, nxt); }
        bf16x8 a[4], b[4];
#pragma unroll
        for (int r = 0; r < 4; r++)
            a[r] = (p < 8) ? *(const bf16x8*)&As[cur][16 * r + m][quad * 8]
                           : *(const bf16x8*)&heb[16 * r + m][(p - 8) * 32 + quad * 8];
#pragma unroll
        for (int c = 0; c < 4; c++) b[c] = bfr(cur, c);
#pragma unroll
        for (int r = 0; r < 4; r++)
#pragma unroll
            for (int c = 0; c < 4; c++)
                qa[r][c] = __builtin_amdgcn_mfma_f32_16x16x32_bf16(a[r], b[c], qa[r][c], 0, 0, 0);
        __syncthreads();
    }
    // ---- stage 2b: K
    f32x4 ka[4][4];
#pragma unroll
    for (int r = 0; r < 4; r++)
#pragma unroll
        for (int c = 0; c < 4; c++) ka[r][c] = (f32x4){0.f, 0.f, 0.f, 0.f};
    stageH(did, 0, 0); stageB(KP, 0, 0);
    __syncthreads();
    for (int p = 0; p < 16; p++) {
        int cur = p & 1, nxt = cur ^ 1;
        if (p < 15) { stageB(KP, p + 1, nxt); if (p + 1 < 8) stageH(did, p + 1, nxt); }
        bf16x8 a[4], b[4];
#pragma unroll
        for (int r = 0; r < 4; r++)
            a[r] = (p < 8) ? *(const bf16x8*)&As[cur][16 * r + m][quad * 8]
                           : *(const bf16x8*)&heb[16 * r + m][(p - 8) * 32 + quad * 8];
#pragma unroll
        for (int c = 0; c < 4; c++) b[c] = bfr(cur, c);
#pragma unroll
        for (int r = 0; r < 4; r++)
#pragma unroll
            for (int c = 0; c < 4; c++)
                ka[r][c] = __builtin_amdgcn_mfma_f32_16x16x32_bf16(a[r], b[c], ka[r][c], 0, 0, 0);
        __syncthreads();
    }
    // ---- epilogue: head wv scores (this wave's col group IS head wv)
#pragma unroll
    for (int r = 0; r < 4; r++) {
#pragma unroll
        for (int rr = 0; rr < 4; rr++) {
            float sum = 0.f;
#pragma unroll
            for (int c = 0; c < 4; c++) {
                int col = n0 + 16 * c + m;
                sum += (qa[r][c][rr] + bq[col]) * (ka[r][c][rr] + bkv[col]);
            }
            sum += __shfl_xor(sum, 1, 64);
            sum += __shfl_xor(sum, 2, 64);
            sum += __shfl_xor(sum, 4, 64);
            sum += __shfl_xor(sum, 8, 64);
            if (m == 0)
                scores[(size_t)(e0 + 16 * r + quad * 4 + rr) * 4 + wv] = sum * 0.125f;
        }
    }
}

// ---------------- MFMA AV kernel ----------------

__global__ void __launch_bounds__(256) k_av_mfma(
    const bf16* __restrict__ hnb, const int* __restrict__ src, const int* __restrict__ dst,
    const float* __restrict__ frac, const float* __restrict__ shifts,
    const uint4* __restrict__ WeP, const float* __restrict__ be,
    const uint4* __restrict__ VP, const float* __restrict__ bkv,
    const float* __restrict__ w, float* __restrict__ attn) {
    __shared__ bf16 heb[64][HEPAD];
    __shared__ bf16 As[2][64][ASPAD];
    __shared__ bf16 Bsm[2][8192];
    __shared__ float dsv[64][3];
    __shared__ int sid[64], did[64];

    int tid = threadIdx.x;
    int wv = tid >> 6, lane = tid & 63, quad = lane >> 4, m = lane & 15;
    int e0 = blockIdx.x * 64;
    if (tid < 64) {
        int e = e0 + tid;
        int sn = src[e], dn = dst[e];
        sid[tid] = sn; did[tid] = dn;
#pragma unroll
        for (int c = 0; c < 3; c++) {
            float a = frac[dn * 3 + c] - frac[sn * 3 + c] + shifts[e * 3 + c];
            dsv[tid][c] = a - floorf(a);
        }
    }
    __syncthreads();

    int ar = tid >> 2, kb = (tid & 3) * 8;
    float d0 = dsv[ar][0], d1 = dsv[ar][1], d2 = dsv[ar][2];
    int n0 = 64 * wv;

    auto stageF = [&](int p, int buf) {
        bf16 t8[8];
#pragma unroll
        for (int j = 0; j < 8; j++) {
            int k = p * 32 + kb + j;
            float v = 0.f;
            if (k < KF) {
                int jj = (k < 300) ? k : k - 300;
                int c = jj / 100;
                int f = jj - c * 100;
                float d = (c == 0) ? d0 : ((c == 1) ? d1 : d2);
                float ang = 6.283185307179586f * d * (float)f;
                v = (k < 300) ? __sinf(ang) : __cosf(ang);
            }
            t8[j] = f2b(v);
        }
        *(uint4*)&As[buf][ar][kb] = *(const uint4*)t8;
    };
    auto stageH = [&](const int* ids, int p, int buf) {
        *(uint4*)&As[buf][ar][kb] = *(const uint4*)&hnb[(size_t)ids[ar] * 256 + p * 32 + kb];
    };
    auto stageB = [&](const uint4* P, int p, int buf) {
        const uint4* g = P + (size_t)p * 1024;
        uint4* s = (uint4*)&Bsm[buf][0];
#pragma unroll
        for (int i = 0; i < 4; i++) s[tid + i * 256] = g[tid + i * 256];
    };
    auto bfr = [&](int buf, int c) -> bf16x8 {
        int n = n0 + 16 * c + m;
        int q2 = (quad + ((n >> 1) & 3)) & 3;
        return *(const bf16x8*)&Bsm[buf][n * 32 + q2 * 8];
    };

    // ---- stage 1: he
    {
        f32x4 acc[4][4];
#pragma unroll
        for (int r = 0; r < 4; r++)
#pragma unroll
            for (int c = 0; c < 4; c++) acc[r][c] = (f32x4){0.f, 0.f, 0.f, 0.f};
        stageF(0, 0); stageB(WeP, 0, 0);
        __syncthreads();
        for (int p = 0; p < 19; p++) {
            int cur = p & 1, nxt = cur ^ 1;
            if (p < 18) { stageF(p + 1, nxt); stageB(WeP, p + 1, nxt); }
            bf16x8 a[4], b[4];
#pragma unroll
            for (int r = 0; r < 4; r++) a[r] = *(const bf16x8*)&As[cur][16 * r + m][quad * 8];
#pragma unroll
            for (int c = 0; c < 4; c++) b[c] = bfr(cur, c);
#pragma unroll
            for (int r = 0; r < 4; r++)
#pragma unroll
                for (int c = 0; c < 4; c++)
                    acc[r][c] = __builtin_amdgcn_mfma_f32_16x16x32_bf16(a[r], b[c], acc[r][c], 0, 0, 0);
            __syncthreads();
        }
#pragma unroll
        for (int r = 0; r < 4; r++)
#pragma unroll
            for (int c = 0; c < 4; c++) {
                int col = n0 + 16 * c + m;
                float bias = be[col];
#pragma unroll
                for (int rr = 0; rr < 4; rr++)
                    heb[16 * r + quad * 4 + rr][col] = f2b(acc[r][c][rr] + bias);
            }
    }
    __syncthreads();

    // ---- stage 2: V
    f32x4 va[4][4];
#pragma unroll
    for (int r = 0; r < 4; r++)
#pragma unroll
        for (int c = 0; c < 4; c++) va[r][c] = (f32x4){0.f, 0.f, 0.f, 0.f};
    stageH(did, 0, 0); stageB(VP, 0, 0);
    __syncthreads();
    for (int p = 0; p < 16; p++) {
        int cur = p & 1, nxt = cur ^ 1;
        if (p < 15) { stageB(VP, p + 1, nxt); if (p + 1 < 8) stageH(did, p + 1, nxt); }
        bf16x8 a[4], b[4];
#pragma unroll
        for (int r = 0; r < 4; r++)
            a[r] = (p < 8) ? *(const bf16x8*)&As[cur][16 * r + m][quad * 8]
                           : *(const bf16x8*)&heb[16 * r + m][(p - 8) * 32 + quad * 8];
#pragma unroll
        for (int c = 0; c < 4; c++) b[c] = bfr(cur, c);
#pragma unroll
        for (int r = 0; r < 4; r++)
#pragma unroll
            for (int c = 0; c < 4; c++)
                va[r][c] = __builtin_amdgcn_mfma_f32_16x16x32_bf16(a[r], b[c], va[r][c], 0, 0, 0);
        __syncthreads();
    }
    // ---- epilogue: weighted atomic scatter (head = wv)
    float wr[4][4];
#pragma unroll
    for (int r = 0; r < 4; r++)
#pragma unroll
        for (int rr = 0; rr < 4; rr++)
            wr[r][rr] = w[(size_t)(e0 + 16 * r + quad * 4 + rr) * 4 + wv];
#pragma unroll
    for (int r = 0; r < 4; r++)
#pragma unroll
        for (int c = 0; c < 4; c++) {
            int col = n0 + 16 * c + m;
            float vb = bkv[256 + col];
#pragma unroll
            for (int rr = 0; rr < 4; rr++) {
                int row = 16 * r + quad * 4 + rr;
                atomicAdd(&attn[(size_t)sid[row] * 256 + col], wr[r][rr] * (va[r][c][rr] + vb));
            }
        }
}

// ---------------- node GEMM via MFMA (64-row tiles, 4x4 reuse) ----------------

template <int OUTB>
__global__ void __launch_bounds__(256) k_gnode(
    const bf16* __restrict__ Ab, int lda, const uint4* __restrict__ P, int ksteps,
    const float* __restrict__ bias, int act, float* __restrict__ Cf,
    bf16* __restrict__ Cb, int ldc) {
    __shared__ bf16 As[2][64][ASPAD];
    __shared__ bf16 Bsm[2][8192];
    int tid = threadIdx.x;
    int wv = tid >> 6, lane = tid & 63, quad = lane >> 4, m = lane & 15;
    int m0 = blockIdx.x * 64, g = blockIdx.y;
    const uint4* Pg = P + (size_t)g * ksteps * 1024;
    int ar = tid >> 2, kb = (tid & 3) * 8;
    int n0 = 64 * wv;

    auto stageA = [&](int p, int buf) {
        *(uint4*)&As[buf][ar][kb] = *(const uint4*)&Ab[(size_t)(m0 + ar) * lda + p * 32 + kb];
    };
    auto stageB = [&](int p, int buf) {
        const uint4* gp = Pg + (size_t)p * 1024;
        uint4* s = (uint4*)&Bsm[buf][0];
#pragma unroll
        for (int i = 0; i < 4; i++) s[tid + i * 256] = gp[tid + i * 256];
    };
    auto bfr = [&](int buf, int c) -> bf16x8 {
        int n = n0 + 16 * c + m;
        int q2 = (quad + ((n >> 1) & 3)) & 3;
        return *(const bf16x8*)&Bsm[buf][n * 32 + q2 * 8];
    };

    f32x4 acc[4][4];
#pragma unroll
    for (int r = 0; r < 4; r++)
#pragma unroll
        for (int c = 0; c < 4; c++) acc[r][c] = (f32x4){0.f, 0.f, 0.f, 0.f};
    stageA(0, 0); stageB(0, 0);
    __syncthreads();
    for (int p = 0; p < ksteps; p++) {
        int cur = p & 1, nxt = cur ^ 1;
        if (p < ksteps - 1) { stageA(p + 1, nxt); stageB(p + 1, nxt); }
        bf16x8 a[4], b[4];
#pragma unroll
        for (int r = 0; r < 4; r++) a[r] = *(const bf16x8*)&As[cur][16 * r + m][quad * 8];
#pragma unroll
        for (int c = 0; c < 4; c++) b[c] = bfr(cur, c);
#pragma unroll
        for (int r = 0; r < 4; r++)
#pragma unroll
            for (int c = 0; c < 4; c++)
                acc[r][c] = __builtin_amdgcn_mfma_f32_16x16x32_bf16(a[r], b[c], acc[r][c], 0, 0, 0);
        __syncthreads();
    }
#pragma unroll
    for (int r = 0; r < 4; r++)
#pragma unroll
        for (int c = 0; c < 4; c++) {
            int col = g * 256 + n0 + 16 * c + m;
            float bb = bias ? bias[col] : 0.f;
#pragma unroll
            for (int rr = 0; rr < 4; rr++) {
                int row = m0 + 16 * r + quad * 4 + rr;
                float v = acc[r][c][rr] + bb;
                if (act) v = 0.5f * v * (1.0f + erff(v * 0.7071067811865475f));
                if (OUTB) Cb[(size_t)row * ldc + col] = f2b(v);
                else Cf[(size_t)row * ldc + col] = v;
            }
        }
}

// ---------------- segment softmax ----------------

__global__ void k_softmax(const int* __restrict__ starts, const int* __restrict__ eids,
                          float* __restrict__ scores) {
    int n = blockIdx.x;
    int s0 = starts[n], s1 = starts[n + 1];
    int h = threadIdx.x >> 6, lane = threadIdx.x & 63;
    float mx = -1e30f;
    for (int i = s0 + lane; i < s1; i += 64) mx = fmaxf(mx, scores[eids[i] * 4 + h]);
    for (int m = 32; m >= 1; m >>= 1) mx = fmaxf(mx, __shfl_xor(mx, m, 64));
    float den = 0.f;
    for (int i = s0 + lane; i < s1; i += 64) den += expf(scores[eids[i] * 4 + h] - mx);
    for (int m = 32; m >= 1; m >>= 1) den += __shfl_xor(den, m, 64);
    float inv = 1.0f / den;
    for (int i = s0 + lane; i < s1; i += 64) {
        int e = eids[i];
        scores[e * 4 + h] = expf(scores[e * 4 + h] - mx) * inv;
    }
}

// ---------------- residual + layernorm (fused bf16 out) ----------------

__global__ void k_add_ln(float* __restrict__ h, const float* __restrict__ r,
                         const float* __restrict__ g, const float* __restrict__ b,
                         bf16* __restrict__ hb) {
    __shared__ float red[4];
    int n = blockIdx.x, d = threadIdx.x;
    float x = h[n * DD + d] + r[n * DD + d];
    float v = x;
    for (int m = 32; m >= 1; m >>= 1) v += __shfl_xor(v, m, 64);
    if ((d & 63) == 0) red[d >> 6] = v;
    __syncthreads();
    float mu = (red[0] + red[1] + red[2] + red[3]) * (1.0f / 256.0f);
    __syncthreads();
    float t = x - mu;
    v = t * t;
    for (int m = 32; m >= 1; m >>= 1) v += __shfl_xor(v, m, 64);
    if ((d & 63) == 0) red[d >> 6] = v;
    __syncthreads();
    float var = (red[0] + red[1] + red[2] + red[3]) * (1.0f / 256.0f);
    float y = t * rsqrtf(var + 1e-5f) * g[d] + b[d];
    h[n * DD + d] = y;
    hb[n * DD + d] = f2b(y);
}

__global__ void k_out(const float* __restrict__ h, float* __restrict__ out) {
    int i = blockIdx.x * 256 + threadIdx.x;
    if (i < NN * DD) out[i] = h[i];
}

// ---------------- launch ----------------

extern "C" void kernel_launch(void* const* d_in, const int* in_sizes, int n_in,
                              void* d_out, int out_size, void* d_ws, size_t ws_size,
                              hipStream_t stream) {
    const int* atom_types = (const int*)d_in[0];
    const float* lattices = (const float*)d_in[1];
    const float* frac = (const float*)d_in[2];
    const int* eidx = (const int*)d_in[3];
    const float* shifts = (const float*)d_in[4];
    const int* batch_ids = (const int*)d_in[5];
    const float* atom_emb = (const float*)d_in[6];
    const float* node_W = (const float*)d_in[7];
    const float* node_b = (const float*)d_in[8];
    const float* edge_W = (const float*)d_in[9];
    const float* edge_b = (const float*)d_in[10];
    const float* Wq = (const float*)d_in[11];
    const float* bq = (const float*)d_in[12];
    const float* Wkv = (const float*)d_in[13];
    const float* bkv = (const float*)d_in[14];
    const float* Wo = (const float*)d_in[15];
    const float* bo = (const float*)d_in[16];
    const float* ln1g = (const float*)d_in[17];
    const float* ln1b = (const float*)d_in[18];
    const float* W1 = (const float*)d_in[19];
    const float* b1 = (const float*)d_in[20];
    const float* W2 = (const float*)d_in[21];
    const float* b2w = (const float*)d_in[22];
    const float* ln2g = (const float*)d_in[23];
    const float* ln2b = (const float*)d_in[24];

    char* base = (char*)d_ws;
    size_t off = 0;
    auto alloc = [&](size_t bytes) -> void* {
        void* p = base + off;
        off = (off + bytes + 255) & ~(size_t)255;
        return p;
    };
    int* counts = (int*)alloc((size_t)NN * 4);
    int* cursor = (int*)alloc((size_t)NN * 4);
    int* starts = (int*)alloc((size_t)(NN + 1) * 4);
    int* eids = (int*)alloc((size_t)EE * 4);
    float* lfeat = (float*)alloc((size_t)BB * 6 * 4);
    float* h_n = (float*)alloc((size_t)NN * DD * 4);
    float* attn = (float*)alloc((size_t)NN * DD * 4);
    float* tmp = (float*)alloc((size_t)NN * DD * 4);
    float* scores = tmp;
    bf16* hnb = (bf16*)alloc((size_t)NN * DD * 2);
    bf16* attnb = (bf16*)alloc((size_t)NN * DD * 2);
    bf16* h1b = (bf16*)alloc((size_t)NN * 1024 * 2);
    bf16* WeP = (bf16*)alloc((size_t)19 * 8192 * 2);
    bf16* QP = (bf16*)alloc((size_t)LL * 16 * 8192 * 2);
    bf16* KP = (bf16*)alloc((size_t)LL * 16 * 8192 * 2);
    bf16* VP = (bf16*)alloc((size_t)LL * 16 * 8192 * 2);
    bf16* WoP = (bf16*)alloc((size_t)LL * 8 * 8192 * 2);
    bf16* W1P = (bf16*)alloc((size_t)LL * 32 * 8192 * 2);
    bf16* W2P = (bf16*)alloc((size_t)LL * 32 * 8192 * 2);

    const int* src = eidx;
    const int* dstp = eidx + EE;

    k_lfeat<<<1, 96, 0, stream>>>(lattices, lfeat);
    k_zero<<<(NN + 255) / 256, 256, 0, stream>>>(counts, NN);
    k_count<<<(EE + 255) / 256, 256, 0, stream>>>(src, counts);
    k_scan<<<1, 256, 0, stream>>>(counts, starts, cursor);
    k_scatter<<<(EE + 255) / 256, 256, 0, stream>>>(src, cursor, eids);
    k_node_init<<<NN, 256, 0, stream>>>(atom_types, batch_ids, atom_emb, node_W, node_b,
                                        lfeat, h_n);
    k_cvt<<<(NN * DD + 255) / 256, 256, 0, stream>>>(h_n, hnb, NN * DD);

    k_panel<<<dim3(19, 1, 1), 256, 0, stream>>>(edge_W, 256, 0, 0, KF, WeP, 19);
    k_panel<<<dim3(16, LL, 1), 256, 0, stream>>>(Wq, 256, 0, 512 * 256, 512, QP, 16);
    k_panel<<<dim3(16, LL, 1), 256, 0, stream>>>(Wkv, 512, 0, 512 * 512, 512, KP, 16);
    k_panel<<<dim3(16, LL, 1), 256, 0, stream>>>(Wkv, 512, 256, 512 * 512, 512, VP, 16);
    k_panel<<<dim3(8, LL, 1), 256, 0, stream>>>(Wo, 256, 0, 256 * 256, 256, WoP, 8);
    k_panel<<<dim3(8, LL, 4), 256, 0, stream>>>(W1, 1024, 0, 256 * 1024, 256, W1P, 8);
    k_panel<<<dim3(32, LL, 1), 256, 0, stream>>>(W2, 256, 0, 1024 * 256, 1024, W2P, 32);

    for (int l = 0; l < LL; l++) {
        const uint4* QPl = (const uint4*)(QP + (size_t)l * 16 * 8192);
        const uint4* KPl = (const uint4*)(KP + (size_t)l * 16 * 8192);
        const uint4* VPl = (const uint4*)(VP + (size_t)l * 16 * 8192);
        const uint4* WoPl = (const uint4*)(WoP + (size_t)l * 8 * 8192);
        const uint4* W1Pl = (const uint4*)(W1P + (size_t)l * 32 * 8192);
        const uint4* W2Pl = (const uint4*)(W2P + (size_t)l * 32 * 8192);

        k_qk_mfma<<<EE / 64, 256, 0, stream>>>(hnb, src, dstp, frac, shifts,
                                               (const uint4*)WeP, edge_b, QPl, KPl,
                                               bq + l * 256, bkv + l * 512, scores);
        k_softmax<<<NN, 256, 0, stream>>>(starts, eids, scores);
        k_zerof<<<(NN * DD + 255) / 256, 256, 0, stream>>>(attn, NN * DD);
        k_av_mfma<<<EE / 64, 256, 0, stream>>>(hnb, src, dstp, frac, shifts,
                                               (const uint4*)WeP, edge_b, VPl,
                                               bkv + l * 512, scores, attn);
        k_cvt<<<(NN * DD + 255) / 256, 256, 0, stream>>>(attn, attnb, NN * DD);
        k_gnode<0><<<dim3(NN / 64, 1), 256, 0, stream>>>(attnb, 256, WoPl, 8,
                                                         bo + l * 256, 0, tmp, nullptr, 256);
        k_add_ln<<<NN, 256, 0, stream>>>(h_n, tmp, ln1g + l * 256, ln1b + l * 256, hnb);
        k_gnode<1><<<dim3(NN / 64, 4), 256, 0, stream>>>(hnb, 256, W1Pl, 8,
                                                         b1 + l * 1024, 1, nullptr, h1b, 1024);
        k_gnode<0><<<dim3(NN / 64, 1), 256, 0, stream>>>(h1b, 1024, W2Pl, 32,
                                                         b2w + l * 256, 0, tmp, nullptr, 256);
        k_add_ln<<<NN, 256, 0, stream>>>(h_n, tmp, ln2g + l * 256, ln2b + l * 256, hnb);
    }
    k_out<<<(NN * DD + 255) / 256, 256, 0, stream>>>(h_n, (float*)d_out);
}